// Round 4
// baseline (273.773 us; speedup 1.0000x reference)
//
#include <hip/hip_runtime.h>
#include <hip/hip_bf16.h>
#include <math.h>

#define LVL 10
#define TBL 65536u
#define KS 4
#define HIDN 64
#define OUTD 29
#define DIN 40            // L*F, col = f*LVL + l

struct ResArr { float r[LVL]; };

__device__ __forceinline__ float selu_f(float v) {
    const float sc = 1.0507009873554805f;
    const float sa = 1.7580993408473766f;
    return v > 0.f ? sc * v : sa * expm1f(v);
}

// ---------------- kernel 1: hash-grid gather, k-in-lane ----------------
// lane layout: lane = 4*ptInWave + k  (16 points x 4 samples per wave)
// features written column-major: ws[(f*LVL+l)*npts + pt]
__global__ __launch_bounds__(256) void ingp_gather(
    const float* __restrict__ xg, const float* __restrict__ crg,
    const float* __restrict__ epsg, const float* __restrict__ table,
    float* __restrict__ ws, int npts, ResArr res)
{
    const int t    = threadIdx.x;
    const int lane = t & 63;
    const int wv   = t >> 6;
    const int k    = lane & 3;
    const int pg   = blockIdx.x * 64 + wv * 16 + (lane >> 2);
    if (pg >= npts) return;

    const float crv = crg[pg];
    const float tc  = 0.3f * crv;
    const float cvx = fmaf(4.f, xg[pg*3+0], -2.f);
    const float cvy = fmaf(4.f, xg[pg*3+1], -2.f);
    const float cvz = fmaf(4.f, xg[pg*3+2], -2.f);
    const float* ep = epsg + ((size_t)pg * KS + k) * 3;
    const float sx = fmaf(fminf(fmaxf(fmaf(ep[0], tc, cvx), -1.f), 1.f), 0.25f, 0.5f);
    const float sy = fmaf(fminf(fmaxf(fmaf(ep[1], tc, cvy), -1.f), 1.f), 0.25f, 0.5f);
    const float sz = fmaf(fminf(fmaxf(fmaf(ep[2], tc, cvz), -1.f), 1.f), 0.25f, 0.5f);

#pragma unroll
    for (int l = 0; l < LVL; ++l) {
        const float rs = res.r[l];
        const float xs = sx * rs, ys = sy * rs, zs = sz * rs;
        const float fx = floorf(xs), fy = floorf(ys), fz = floorf(zs);
        const float frx = xs - fx, fry = ys - fy, frz = zs - fz;
        const unsigned cx = (unsigned)fx, cy = (unsigned)fy, cz = (unsigned)fz;
        const unsigned hx0 = cx,               hx1 = cx + 1u;
        const unsigned hy0 = cy * 2654435761u, hy1 = hy0 + 2654435761u;
        const unsigned hz0 = cz * 805459861u,  hz1 = hz0 + 805459861u;
        const float wx1 = frx, wx0 = 1.f - frx;
        const float wy1 = fry, wy0 = 1.f - fry;
        const float wz1 = frz, wz0 = 1.f - frz;
        const float4* tl = (const float4*)table + (size_t)l * TBL;
        float4 a = make_float4(0.f, 0.f, 0.f, 0.f);
#define CORNER(HX,HY,HZ,WX,WY,WZ) do { \
            unsigned id = ((HX) ^ (HY) ^ (HZ)) & (TBL - 1u); \
            float4 f = tl[id]; \
            float w = (WX) * (WY) * (WZ); \
            a.x = fmaf(w, f.x, a.x); a.y = fmaf(w, f.y, a.y); \
            a.z = fmaf(w, f.z, a.z); a.w = fmaf(w, f.w, a.w); \
        } while (0)
        CORNER(hx0, hy0, hz0, wx0, wy0, wz0);
        CORNER(hx0, hy0, hz1, wx0, wy0, wz1);
        CORNER(hx0, hy1, hz0, wx0, wy1, wz0);
        CORNER(hx0, hy1, hz1, wx0, wy1, wz1);
        CORNER(hx1, hy0, hz0, wx1, wy0, wz0);
        CORNER(hx1, hy0, hz1, wx1, wy0, wz1);
        CORNER(hx1, hy1, hz0, wx1, wy1, wz0);
        CORNER(hx1, hy1, hz1, wx1, wy1, wz1);
#undef CORNER
        // reduce over the 4 k-lanes (butterfly)
        a.x += __shfl_xor(a.x, 1, 64); a.y += __shfl_xor(a.y, 1, 64);
        a.z += __shfl_xor(a.z, 1, 64); a.w += __shfl_xor(a.w, 1, 64);
        a.x += __shfl_xor(a.x, 2, 64); a.y += __shfl_xor(a.y, 2, 64);
        a.z += __shfl_xor(a.z, 2, 64); a.w += __shfl_xor(a.w, 2, 64);
        if (k == 0) {
            const float den = fmaxf(8.f * (float)l * crv, 1e-12f);
            const float s = 0.25f * erff(rsqrtf(den));   // mean(K) * window
            ws[(size_t)(0*LVL + l) * npts + pg] = a.x * s;
            ws[(size_t)(1*LVL + l) * npts + pg] = a.y * s;
            ws[(size_t)(2*LVL + l) * npts + pg] = a.z * s;
            ws[(size_t)(3*LVL + l) * npts + pg] = a.w * s;
        }
    }
}

// ---------------- kernel 2: MLP + epilogue, thread = point ----------------
__global__ __launch_bounds__(256) void ingp_mlp(
    const float* __restrict__ ws,
    const float* __restrict__ W1, const float* __restrict__ b1,
    const float* __restrict__ W2, const float* __restrict__ b2,
    const float* __restrict__ W3, const float* __restrict__ b3,
    float* __restrict__ out, int npts)
{
    const int p = blockIdx.x * blockDim.x + threadIdx.x;
    if (p >= npts) return;

    float h[DIN];
#pragma unroll
    for (int i = 0; i < DIN; ++i) h[i] = ws[(size_t)i * npts + p];  // coalesced

    float h1[HIDN];
#pragma unroll
    for (int j = 0; j < HIDN; ++j) {
        float acc = b1[j];
#pragma unroll
        for (int i = 0; i < DIN; ++i) acc = fmaf(h[i], W1[j*DIN + i], acc);
        h1[j] = selu_f(acc);
    }
    float h2[HIDN];
#pragma unroll
    for (int j = 0; j < HIDN; ++j) {
        float acc = b2[j];
#pragma unroll
        for (int i = 0; i < HIDN; ++i) acc = fmaf(h1[i], W2[j*HIDN + i], acc);
        h2[j] = selu_f(acc);
    }
    float o[OUTD];
#pragma unroll
    for (int j = 0; j < OUTD; ++j) {
        float acc = b3[j];
#pragma unroll
        for (int i = 0; i < HIDN; ++i) acc = fmaf(h2[i], W3[j*HIDN + i], acc);
        o[j] = acc;
    }

    float* dns  = out;
    float* rgbp = out + (size_t)npts;
    float* grdp = out + (size_t)npts * 4;
    float* shp  = out + (size_t)npts * 13;

    dns[p] = expf(o[0] - 4.f);
    float rr[3];
#pragma unroll
    for (int c = 0; c < 3; ++c) {
        rr[c] = o[1 + c] + 0.5f;
        rgbp[(size_t)p*3 + c] = rr[c];
    }
#pragma unroll
    for (int r = 0; r < 3; ++r)
#pragma unroll
        for (int c = 0; c < 3; ++c)
            grdp[(size_t)p*9 + r*3 + c] = rr[r] * tanhf(o[4 + r*3 + c]);
#pragma unroll
    for (int s = 0; s < 16; ++s)
        shp[(size_t)p*16 + s] = o[13 + s];
}

extern "C" void kernel_launch(void* const* d_in, const int* in_sizes, int n_in,
                              void* d_out, int out_size, void* d_ws, size_t ws_size,
                              hipStream_t stream) {
    const float* x     = (const float*)d_in[0];
    const float* cr    = (const float*)d_in[1];
    const float* eps   = (const float*)d_in[2];
    const float* table = (const float*)d_in[3];
    const float* W1    = (const float*)d_in[4];
    const float* b1    = (const float*)d_in[5];
    const float* W2    = (const float*)d_in[6];
    const float* b2    = (const float*)d_in[7];
    const float* W3    = (const float*)d_in[8];
    const float* b3    = (const float*)d_in[9];
    float* out = (float*)d_out;
    float* ws  = (float*)d_ws;      // needs DIN * npts * 4 bytes = 21 MB

    const int npts = in_sizes[0] / 3;

    ResArr res;
    const double bg = exp(log(pow(2.0, 10.0)) / 9.0);
    for (int l = 0; l < LVL; ++l) res.r[l] = (float)floor(16.0 * pow(bg, (double)l));

    // kernel 1: 64 points per 256-thread block (16 pts x 4 k per wave)
    const int grid1 = (npts + 63) / 64;
    hipLaunchKernelGGL(ingp_gather, dim3(grid1), dim3(256), 0, stream,
                       x, cr, eps, table, ws, npts, res);

    // kernel 2: thread = point
    const int grid2 = (npts + 255) / 256;
    hipLaunchKernelGGL(ingp_mlp, dim3(grid2), dim3(256), 0, stream,
                       ws, W1, b1, W2, b2, W3, b3, out, npts);
}

// Round 6
// 190.636 us; speedup vs baseline: 1.4361x; 1.4361x over previous
//
#include <hip/hip_runtime.h>
#include <hip/hip_bf16.h>
#include <math.h>

#define LVL 10
#define TBL 65536u
#define KS 4
#define HIDN 64
#define OUTD 29
#define DIN 40

typedef __attribute__((ext_vector_type(8))) short short8;
typedef __attribute__((ext_vector_type(4))) float f32x4;

struct ResArr { float r[LVL]; };

__device__ __forceinline__ unsigned short f2bf(float v) {
    __hip_bfloat16 b = __float2bfloat16(v);
    return __builtin_bit_cast(unsigned short, b);
}

__device__ __forceinline__ float selu_f(float v) {
    return v > 0.f ? 1.0507009873554805f * v
                   : 1.7580993408473766f * (__expf(v) - 1.f);
}

// ---------------- kernel 1: gather -> bf16 B-fragment-swizzled features ----
// wave = one 16-point tile; lane = 4*c + k  (c = point-in-tile, k = sample)
// hswz layout per tile (1024 shorts = 2KB): [ks(2)][laneq(4)][c(16)][j(8)]
//   feature f (=comp*LVL+l): ks=f>>5, laneq=(f>>3)&3, j=f&7 ; K padded 40->64 (zeros)
__global__ __launch_bounds__(256, 4) void ingp_gather(
    const float* __restrict__ xg, const float* __restrict__ crg,
    const float* __restrict__ epsg, const float* __restrict__ table,
    unsigned short* __restrict__ hswz, int npts, ResArr res)
{
    const int t    = threadIdx.x;
    const int lane = t & 63;
    const int wv   = t >> 6;
    const int k    = lane & 3;
    const int c    = lane >> 2;
    const int tile = blockIdx.x * 4 + wv;
    const int pg   = tile * 16 + c;
    if (pg >= npts) return;

    unsigned short* tb = hswz + (size_t)tile * 1024;
    // zero the K-pad region (features 40..63 -> shorts [640,1024) = 192 dwords)
    {
        unsigned* z = (unsigned*)(tb + 640);
        z[lane] = 0u; z[lane + 64] = 0u; z[lane + 128] = 0u;
    }

    const float crv = crg[pg];
    const float tc  = 0.3f * crv;
    const float cvx = fmaf(4.f, xg[pg*3+0], -2.f);
    const float cvy = fmaf(4.f, xg[pg*3+1], -2.f);
    const float cvz = fmaf(4.f, xg[pg*3+2], -2.f);
    const float* ep = epsg + ((size_t)pg * KS + k) * 3;
    const float sx = fmaf(fminf(fmaxf(fmaf(ep[0], tc, cvx), -1.f), 1.f), 0.25f, 0.5f);
    const float sy = fmaf(fminf(fmaxf(fmaf(ep[1], tc, cvy), -1.f), 1.f), 0.25f, 0.5f);
    const float sz = fmaf(fminf(fmaxf(fmaf(ep[2], tc, cvz), -1.f), 1.f), 0.25f, 0.5f);

#pragma unroll
    for (int l = 0; l < LVL; ++l) {
        const float rs = res.r[l];
        const float xs = sx * rs, ys = sy * rs, zs = sz * rs;
        const float fx = floorf(xs), fy = floorf(ys), fz = floorf(zs);
        const float frx = xs - fx, fry = ys - fy, frz = zs - fz;
        const unsigned cx = (unsigned)fx, cy = (unsigned)fy, cz = (unsigned)fz;
        const unsigned hx0 = cx,               hx1 = cx + 1u;
        const unsigned hy0 = cy * 2654435761u, hy1 = hy0 + 2654435761u;
        const unsigned hz0 = cz * 805459861u,  hz1 = hz0 + 805459861u;
        const unsigned i0 = (hx0^hy0^hz0) & (TBL-1u);
        const unsigned i1 = (hx0^hy0^hz1) & (TBL-1u);
        const unsigned i2 = (hx0^hy1^hz0) & (TBL-1u);
        const unsigned i3 = (hx0^hy1^hz1) & (TBL-1u);
        const unsigned i4 = (hx1^hy0^hz0) & (TBL-1u);
        const unsigned i5 = (hx1^hy0^hz1) & (TBL-1u);
        const unsigned i6 = (hx1^hy1^hz0) & (TBL-1u);
        const unsigned i7 = (hx1^hy1^hz1) & (TBL-1u);
        const float4* tl = (const float4*)table + (size_t)l * TBL;
        // batch all 8 loads (independent -> stay in flight together)
        const float4 f0 = tl[i0], f1 = tl[i1], f2 = tl[i2], f3 = tl[i3];
        const float4 f4 = tl[i4], f5 = tl[i5], f6 = tl[i6], f7 = tl[i7];
        const float wx1 = frx, wx0 = 1.f - frx;
        const float wy1 = fry, wy0 = 1.f - fry;
        const float wz1 = frz, wz0 = 1.f - frz;
        const float w0 = wx0*wy0*wz0, w1 = wx0*wy0*wz1, w2 = wx0*wy1*wz0, w3 = wx0*wy1*wz1;
        const float w4 = wx1*wy0*wz0, w5 = wx1*wy0*wz1, w6 = wx1*wy1*wz0, w7 = wx1*wy1*wz1;
        float ax = w0*f0.x + w1*f1.x + w2*f2.x + w3*f3.x + w4*f4.x + w5*f5.x + w6*f6.x + w7*f7.x;
        float ay = w0*f0.y + w1*f1.y + w2*f2.y + w3*f3.y + w4*f4.y + w5*f5.y + w6*f6.y + w7*f7.y;
        float az = w0*f0.z + w1*f1.z + w2*f2.z + w3*f3.z + w4*f4.z + w5*f5.z + w6*f6.z + w7*f7.z;
        float aw = w0*f0.w + w1*f1.w + w2*f2.w + w3*f3.w + w4*f4.w + w5*f5.w + w6*f6.w + w7*f7.w;
        // reduce over the 4 k-lanes
        ax += __shfl_xor(ax, 1, 64); ay += __shfl_xor(ay, 1, 64);
        az += __shfl_xor(az, 1, 64); aw += __shfl_xor(aw, 1, 64);
        ax += __shfl_xor(ax, 2, 64); ay += __shfl_xor(ay, 2, 64);
        az += __shfl_xor(az, 2, 64); aw += __shfl_xor(aw, 2, 64);
        // mean(K) * window
        const float den = fmaxf(8.f * (float)l * crv, 1e-12f);
        const float s = 0.25f * erff(rsqrtf(den));
        // lane k stores component k of this level
        const float v = (k & 1) ? ((k & 2) ? aw : ay) : ((k & 2) ? az : ax);
        const int f = k * LVL + l;
        const int a = ((f >> 5) << 9) + (((f >> 3) & 3) << 7) + (c << 3) + (f & 7);
        tb[a] = f2bf(v * s);
    }
}

// ---------------- kernel 2: MFMA MLP, wave = 16-point tile -------------------
__global__ __launch_bounds__(256, 4) void ingp_mlp(
    const unsigned short* __restrict__ hswz,
    const float* __restrict__ W1, const float* __restrict__ b1,
    const float* __restrict__ W2, const float* __restrict__ b2,
    const float* __restrict__ W3, const float* __restrict__ b3,
    float* __restrict__ out, int npts)
{
    __shared__ __align__(16) char lds[4][2][2304];
    const int t    = threadIdx.x;
    const int lane = t & 63;
    const int wv   = t >> 6;
    const int c    = lane & 15;     // output column (point in tile)
    const int g    = lane >> 4;     // k-group / row-group
    const int tile = blockIdx.x * 4 + wv;
    char* bufA = lds[wv][0];
    char* bufB = lds[wv][1];

    auto ldW = [&](const float* W, int ldw, int row, int kbase) -> short8 {
        const float* p = W + row * ldw + kbase;
        const float4 u = *(const float4*)p;
        const float4 v = *(const float4*)(p + 4);
        short8 r;
        r[0] = (short)f2bf(u.x); r[1] = (short)f2bf(u.y);
        r[2] = (short)f2bf(u.z); r[3] = (short)f2bf(u.w);
        r[4] = (short)f2bf(v.x); r[5] = (short)f2bf(v.y);
        r[6] = (short)f2bf(v.z); r[7] = (short)f2bf(v.w);
        return r;
    };
    const short8 zf = {0,0,0,0,0,0,0,0};

    // ---- GEMM1: h1 = selu(W1 @ h + b1), K=64 (padded) ----
    const short8* Hf = (const short8*)(hswz + (size_t)tile * 1024);
    const short8 hb0 = Hf[lane];
    const short8 hb1 = Hf[64 + lane];
    f32x4 acc[4];
#pragma unroll
    for (int mt = 0; mt < 4; ++mt) {
        const int row = mt * 16 + c;
        const short8 a0 = ldW(W1, DIN, row, g * 8);
        const short8 a1 = (g == 0) ? ldW(W1, DIN, row, 32) : zf;
        f32x4 acr = {0.f, 0.f, 0.f, 0.f};
        acr = __builtin_amdgcn_mfma_f32_16x16x32_bf16(a0, hb0, acr, 0, 0, 0);
        acr = __builtin_amdgcn_mfma_f32_16x16x32_bf16(a1, hb1, acr, 0, 0, 0);
        acc[mt] = acr;
    }
    // D layout: row = mt*16 + g*4 + r, col = c.  Store H1 as [p=c][k] bf16 (stride 72)
#pragma unroll
    for (int mt = 0; mt < 4; ++mt) {
        unsigned short h4[4];
#pragma unroll
        for (int r = 0; r < 4; ++r) {
            const int hrow = mt * 16 + g * 4 + r;
            h4[r] = f2bf(selu_f(acc[mt][r] + b1[hrow]));
        }
        uint2 pk;
        pk.x = (unsigned)h4[0] | ((unsigned)h4[1] << 16);
        pk.y = (unsigned)h4[2] | ((unsigned)h4[3] << 16);
        *(uint2*)(bufA + c * 144 + mt * 32 + g * 8) = pk;
    }
    __syncthreads();

    // ---- GEMM2: h2 = selu(W2 @ h1 + b2), K=64 -> 2 k-slices of 32 ----
    short8 h1f[2];
#pragma unroll
    for (int ks = 0; ks < 2; ++ks)
        h1f[ks] = *(const short8*)(bufA + c * 144 + ks * 64 + g * 16);
    f32x4 acc2[4];
#pragma unroll
    for (int mt = 0; mt < 4; ++mt) {
        f32x4 acr = {0.f, 0.f, 0.f, 0.f};
#pragma unroll
        for (int ks = 0; ks < 2; ++ks) {
            const short8 af = ldW(W2, HIDN, mt * 16 + c, ks * 32 + g * 8);
            acr = __builtin_amdgcn_mfma_f32_16x16x32_bf16(af, h1f[ks], acr, 0, 0, 0);
        }
        acc2[mt] = acr;
    }
    __syncthreads();
#pragma unroll
    for (int mt = 0; mt < 4; ++mt) {
        unsigned short h4[4];
#pragma unroll
        for (int r = 0; r < 4; ++r) {
            const int hrow = mt * 16 + g * 4 + r;
            h4[r] = f2bf(selu_f(acc2[mt][r] + b2[hrow]));
        }
        uint2 pk;
        pk.x = (unsigned)h4[0] | ((unsigned)h4[1] << 16);
        pk.y = (unsigned)h4[2] | ((unsigned)h4[3] << 16);
        *(uint2*)(bufB + c * 144 + mt * 32 + g * 8) = pk;
    }
    __syncthreads();

    // ---- GEMM3: o = W3 @ h2 + b3  (29 rows, padded to 32), K=64 -> 2 slices ----
    short8 h2f[2];
#pragma unroll
    for (int ks = 0; ks < 2; ++ks)
        h2f[ks] = *(const short8*)(bufB + c * 144 + ks * 64 + g * 16);
    f32x4 o0 = {0.f,0.f,0.f,0.f}, o1 = {0.f,0.f,0.f,0.f};
#pragma unroll
    for (int ks = 0; ks < 2; ++ks) {
        const short8 af0 = ldW(W3, HIDN, c, ks * 32 + g * 8);
        o0 = __builtin_amdgcn_mfma_f32_16x16x32_bf16(af0, h2f[ks], o0, 0, 0, 0);
        const int row1 = 16 + c;
        const short8 af1 = (row1 < OUTD) ? ldW(W3, HIDN, row1, ks * 32 + g * 8) : zf;
        o1 = __builtin_amdgcn_mfma_f32_16x16x32_bf16(af1, h2f[ks], o1, 0, 0, 0);
    }
    __syncthreads();   // bufA free again
    {
        f32x4 v0, v1;
#pragma unroll
        for (int r = 0; r < 4; ++r) {
            v0[r] = o0[r] + b3[g * 4 + r];
            const int rw = 16 + g * 4 + r;
            v1[r] = o1[r] + ((rw < OUTD) ? b3[rw] : 0.f);
        }
        *(f32x4*)(bufA + c * 144 + g * 16)      = v0;   // rows g*4..g*4+3
        *(f32x4*)(bufA + c * 144 + 64 + g * 16) = v1;   // rows 16+g*4..
    }
    __syncthreads();

    // ---- epilogue: quad per point (c2 = lane>>2, part = lane&3) ----
    {
        const int c2 = lane >> 2, part = lane & 3;
        const float* op = (const float*)(bufA + c2 * 144);
        const size_t p = (size_t)tile * 16 + c2;
        float* dns  = out;
        float* rgbp = out + (size_t)npts;
        float* grdp = out + (size_t)npts * 4;
        float* shp  = out + (size_t)npts * 13;
        if (part == 0) {
            dns[p] = expf(op[0] - 4.f);
            rgbp[p*3+0] = op[1] + 0.5f;
            rgbp[p*3+1] = op[2] + 0.5f;
            rgbp[p*3+2] = op[3] + 0.5f;
        } else {
            const int r = part - 1;
            const float rr = op[1 + r] + 0.5f;
            grdp[p*9 + r*3 + 0] = rr * tanhf(op[4 + r*3 + 0]);
            grdp[p*9 + r*3 + 1] = rr * tanhf(op[4 + r*3 + 1]);
            grdp[p*9 + r*3 + 2] = rr * tanhf(op[4 + r*3 + 2]);
        }
#pragma unroll
        for (int s = 0; s < 4; ++s)
            shp[p*16 + part*4 + s] = op[13 + part*4 + s];
    }
}

extern "C" void kernel_launch(void* const* d_in, const int* in_sizes, int n_in,
                              void* d_out, int out_size, void* d_ws, size_t ws_size,
                              hipStream_t stream) {
    const float* x     = (const float*)d_in[0];
    const float* cr    = (const float*)d_in[1];
    const float* eps   = (const float*)d_in[2];
    const float* table = (const float*)d_in[3];
    const float* W1    = (const float*)d_in[4];
    const float* b1    = (const float*)d_in[5];
    const float* W2    = (const float*)d_in[6];
    const float* b2    = (const float*)d_in[7];
    const float* W3    = (const float*)d_in[8];
    const float* b3    = (const float*)d_in[9];
    float* out = (float*)d_out;
    unsigned short* hswz = (unsigned short*)d_ws;   // npts/16 tiles * 2KB = 16.8 MB

    const int npts = in_sizes[0] / 3;

    ResArr res;
    const double bg = exp(log(pow(2.0, 10.0)) / 9.0);
    for (int l = 0; l < LVL; ++l) res.r[l] = (float)floor(16.0 * pow(bg, (double)l));

    const int grid = (npts + 63) / 64;   // 64 points (4 tiles) per 256-thread block
    hipLaunchKernelGGL(ingp_gather, dim3(grid), dim3(256), 0, stream,
                       x, cr, eps, table, hswz, npts, res);
    hipLaunchKernelGGL(ingp_mlp, dim3(grid), dim3(256), 0, stream,
                       hswz, W1, b1, W2, b2, W3, b3, out, npts);
}

// Round 7
// 154.700 us; speedup vs baseline: 1.7697x; 1.2323x over previous
//
#include <hip/hip_runtime.h>
#include <hip/hip_bf16.h>
#include <math.h>

#define LVL 10
#define TBL 65536u
#define HIDN 64
#define OUTD 29
#define DIN 40

typedef __attribute__((ext_vector_type(8))) short short8;
typedef __attribute__((ext_vector_type(4))) float f32x4;

struct ResArr { float r[LVL]; };

__device__ __forceinline__ unsigned short f2bf(float v) {
    __hip_bfloat16 b = __float2bfloat16(v);
    return __builtin_bit_cast(unsigned short, b);
}
__device__ __forceinline__ float selu_f(float v) {
    return v > 0.f ? 1.0507009873554805f * v
                   : 1.7580993408473766f * (__expf(v) - 1.f);
}

// ---------- kernel 0a: fp32 table -> bf16 table (d_ws) ----------
__global__ __launch_bounds__(256) void cvt_table(const float4* __restrict__ tbl,
                                                 uint2* __restrict__ tblbf) {
    const int i = blockIdx.x * 256 + threadIdx.x;
    if (i >= (int)(TBL * LVL)) return;
    const float4 f = tbl[i];
    uint2 q;
    q.x = (unsigned)f2bf(f.x) | ((unsigned)f2bf(f.y) << 16);
    q.y = (unsigned)f2bf(f.z) | ((unsigned)f2bf(f.w) << 16);
    tblbf[i] = q;
}

// ---------- kernel 0b: weight/bias fragments (30720 B) ----------
// short8 slots: [0..7] W1(mt,half) | [8..15] W2(mt,ks) | [16..19] W3(rt,ks)
// f32x4 at short-offset 10240: [0..3] b1(mt) | [4..7] b2(mt) | [8..9] b3(rt)
__global__ __launch_bounds__(256) void build_frags(
    const float* __restrict__ W1, const float* __restrict__ b1,
    const float* __restrict__ W2, const float* __restrict__ b2,
    const float* __restrict__ W3, const float* __restrict__ b3,
    unsigned short* __restrict__ frag) {
    const int i = blockIdx.x * 256 + threadIdx.x;
    const int lane = i & 63, c = lane & 15, g = lane >> 4;
    if (i < 1280) {
        const int slot = i >> 6;
        float v[8];
#pragma unroll
        for (int j = 0; j < 8; ++j) v[j] = 0.f;
        if (slot < 8) {
            const int mt = slot >> 1, half = slot & 1, row = mt * 16 + c;
            if (half == 0) { for (int j = 0; j < 8; ++j) v[j] = W1[row*DIN + g*8 + j]; }
            else if (g == 0) { for (int j = 0; j < 8; ++j) v[j] = W1[row*DIN + 32 + j]; }
        } else if (slot < 16) {
            const int s = slot - 8, mt = s >> 1, ks = s & 1, row = mt * 16 + c;
            for (int j = 0; j < 8; ++j) v[j] = W2[row*HIDN + ks*32 + g*8 + j];
        } else {
            const int s = slot - 16, rt = s >> 1, ks = s & 1, row = rt * 16 + c;
            if (row < OUTD) { for (int j = 0; j < 8; ++j) v[j] = W3[row*HIDN + ks*32 + g*8 + j]; }
        }
        short8 r;
#pragma unroll
        for (int j = 0; j < 8; ++j) r[j] = (short)f2bf(v[j]);
        ((short8*)frag)[i] = r;
    } else if (i < 1920) {
        const int s = (i - 1280) >> 6;   // 0..9
        f32x4 v = {0.f, 0.f, 0.f, 0.f};
#pragma unroll
        for (int r = 0; r < 4; ++r) {
            if (s < 4)      v[r] = b1[s*16 + g*4 + r];
            else if (s < 8) v[r] = b2[(s-4)*16 + g*4 + r];
            else { const int row = (s-8)*16 + g*4 + r; v[r] = (row < OUTD) ? b3[row] : 0.f; }
        }
        ((f32x4*)(frag + 10240))[i - 1280] = v;
    }
}

// ---------- kernel 1: gather; thread = (point, k, level-half) ----------
// block 256 = 32 points x (2 level-halves) x (4 k); shfl_xor(1,2) reduces k.
template<bool BF>
__global__ __launch_bounds__(256, 6) void ingp_gather(
    const float* __restrict__ xg, const float* __restrict__ crg,
    const float* __restrict__ epsg, const float* __restrict__ table,
    const uint2* __restrict__ tblbf,
    unsigned short* __restrict__ hswz, int npts, ResArr res)
{
    const int t   = threadIdx.x;
    const int k   = t & 3;
    const int lh  = (t >> 2) & 1;
    const int pib = t >> 3;
    const int pg  = blockIdx.x * 32 + pib;

    {   // zero K-pad (shorts [640,1024)) of this block's 2 tiles
        const int tile0 = blockIdx.x * 2;
        for (int i = t; i < 384; i += 256) {
            const int tl = i / 192, off = i - tl * 192;
            const int tile = tile0 + tl;
            if (tile * 16 < npts)
                ((unsigned*)(hswz + (size_t)tile * 1024 + 640))[off] = 0u;
        }
    }
    if (pg >= npts) return;

    const int tile = pg >> 4, c = pg & 15;
    unsigned short* tb = hswz + (size_t)tile * 1024;

    const float crv = crg[pg];
    const float tc  = 0.3f * crv;
    const float cvx = fmaf(4.f, xg[pg*3+0], -2.f);
    const float cvy = fmaf(4.f, xg[pg*3+1], -2.f);
    const float cvz = fmaf(4.f, xg[pg*3+2], -2.f);
    const float* ep = epsg + ((size_t)pg * 4 + k) * 3;
    const float sx = fmaf(fminf(fmaxf(fmaf(ep[0], tc, cvx), -1.f), 1.f), 0.25f, 0.5f);
    const float sy = fmaf(fminf(fmaxf(fmaf(ep[1], tc, cvy), -1.f), 1.f), 0.25f, 0.5f);
    const float sz = fmaf(fminf(fmaxf(fmaf(ep[2], tc, cvz), -1.f), 1.f), 0.25f, 0.5f);

#pragma unroll
    for (int li = 0; li < 5; ++li) {
        const int l = lh * 5 + li;
        const float rs = lh ? res.r[li + 5] : res.r[li];   // static indices (rule #20)
        const float xs = sx * rs, ys = sy * rs, zs = sz * rs;
        const float fx = floorf(xs), fy = floorf(ys), fz = floorf(zs);
        const float frx = xs - fx, fry = ys - fy, frz = zs - fz;
        const unsigned cx = (unsigned)fx, cy = (unsigned)fy, cz = (unsigned)fz;
        const unsigned hx0 = cx,               hx1 = cx + 1u;
        const unsigned hy0 = cy * 2654435761u, hy1 = hy0 + 2654435761u;
        const unsigned hz0 = cz * 805459861u,  hz1 = hz0 + 805459861u;
        const unsigned i0 = (hx0^hy0^hz0) & (TBL-1u);
        const unsigned i1 = (hx0^hy0^hz1) & (TBL-1u);
        const unsigned i2 = (hx0^hy1^hz0) & (TBL-1u);
        const unsigned i3 = (hx0^hy1^hz1) & (TBL-1u);
        const unsigned i4 = (hx1^hy0^hz0) & (TBL-1u);
        const unsigned i5 = (hx1^hy0^hz1) & (TBL-1u);
        const unsigned i6 = (hx1^hy1^hz0) & (TBL-1u);
        const unsigned i7 = (hx1^hy1^hz1) & (TBL-1u);
        const float wx1 = frx, wx0 = 1.f - frx;
        const float wy1 = fry, wy0 = 1.f - fry;
        const float wz1 = frz, wz0 = 1.f - frz;
        const float w0 = wx0*wy0*wz0, w1 = wx0*wy0*wz1, w2 = wx0*wy1*wz0, w3 = wx0*wy1*wz1;
        const float w4 = wx1*wy0*wz0, w5 = wx1*wy0*wz1, w6 = wx1*wy1*wz0, w7 = wx1*wy1*wz1;
        float ax = 0.f, ay = 0.f, az = 0.f, aw = 0.f;
        if (BF) {
            const uint2* tp = tblbf + (size_t)l * TBL;
            const uint2 q0 = tp[i0], q1 = tp[i1], q2 = tp[i2], q3 = tp[i3];
            const uint2 q4 = tp[i4], q5 = tp[i5], q6 = tp[i6], q7 = tp[i7];
#define CBF(Q,W) do { \
                ax = fmaf(W, __uint_as_float((Q).x << 16),        ax); \
                ay = fmaf(W, __uint_as_float((Q).x & 0xffff0000u), ay); \
                az = fmaf(W, __uint_as_float((Q).y << 16),        az); \
                aw = fmaf(W, __uint_as_float((Q).y & 0xffff0000u), aw); } while (0)
            CBF(q0,w0); CBF(q1,w1); CBF(q2,w2); CBF(q3,w3);
            CBF(q4,w4); CBF(q5,w5); CBF(q6,w6); CBF(q7,w7);
#undef CBF
        } else {
            const float4* tp = (const float4*)table + (size_t)l * TBL;
            const float4 f0 = tp[i0], f1 = tp[i1], f2 = tp[i2], f3 = tp[i3];
            const float4 f4 = tp[i4], f5 = tp[i5], f6 = tp[i6], f7 = tp[i7];
#define CF(F,W) do { \
                ax = fmaf(W, (F).x, ax); ay = fmaf(W, (F).y, ay); \
                az = fmaf(W, (F).z, az); aw = fmaf(W, (F).w, aw); } while (0)
            CF(f0,w0); CF(f1,w1); CF(f2,w2); CF(f3,w3);
            CF(f4,w4); CF(f5,w5); CF(f6,w6); CF(f7,w7);
#undef CF
        }
        // reduce over the 4 k-lanes
        ax += __shfl_xor(ax, 1, 64); ay += __shfl_xor(ay, 1, 64);
        az += __shfl_xor(az, 1, 64); aw += __shfl_xor(aw, 1, 64);
        ax += __shfl_xor(ax, 2, 64); ay += __shfl_xor(ay, 2, 64);
        az += __shfl_xor(az, 2, 64); aw += __shfl_xor(aw, 2, 64);
        // mean(K) * window; lane k stores component k
        const float den = fmaxf(8.f * (float)l * crv, 1e-12f);
        const float s = 0.25f * erff(rsqrtf(den));
        const float v = (k & 1) ? ((k & 2) ? aw : ay) : ((k & 2) ? az : ax);
        const int f = k * LVL + l;
        const int a = ((f >> 5) << 9) + (((f >> 3) & 3) << 7) + (c << 3) + (f & 7);
        tb[a] = f2bf(v * s);
    }
}

// ---------- kernel 2: MFMA MLP, wave = 16-point tile ----------
__global__ __launch_bounds__(256, 4) void ingp_mlp(
    const unsigned short* __restrict__ hswz,
    const unsigned short* __restrict__ frag,
    float* __restrict__ out, int npts)
{
    __shared__ __align__(16) char lds[4][2][2304];
    const int t    = threadIdx.x;
    const int lane = t & 63;
    const int wv   = t >> 6;
    const int c    = lane & 15;
    const int g    = lane >> 4;
    const int tile = blockIdx.x * 4 + wv;
    char* bufA = lds[wv][0];
    char* bufB = lds[wv][1];

    const short8* Fa = (const short8*)frag;
    const f32x4*  Fb = (const f32x4*)(frag + 10240);

    // ---- GEMM1: h1 = selu(W1 @ h + b1), K=64 (padded) ----
    const short8* Hf = (const short8*)(hswz + (size_t)tile * 1024);
    const short8 hb0 = Hf[lane];
    const short8 hb1 = Hf[64 + lane];
    f32x4 acc[4];
#pragma unroll
    for (int mt = 0; mt < 4; ++mt) {
        const short8 a0 = Fa[(mt*2    )*64 + lane];
        const short8 a1 = Fa[(mt*2 + 1)*64 + lane];
        f32x4 acr = {0.f, 0.f, 0.f, 0.f};
        acr = __builtin_amdgcn_mfma_f32_16x16x32_bf16(a0, hb0, acr, 0, 0, 0);
        acr = __builtin_amdgcn_mfma_f32_16x16x32_bf16(a1, hb1, acr, 0, 0, 0);
        acc[mt] = acr;
    }
#pragma unroll
    for (int mt = 0; mt < 4; ++mt) {
        const f32x4 bb = Fb[mt*64 + lane];
        unsigned short h4[4];
#pragma unroll
        for (int r = 0; r < 4; ++r) h4[r] = f2bf(selu_f(acc[mt][r] + bb[r]));
        uint2 pk;
        pk.x = (unsigned)h4[0] | ((unsigned)h4[1] << 16);
        pk.y = (unsigned)h4[2] | ((unsigned)h4[3] << 16);
        *(uint2*)(bufA + c * 144 + mt * 32 + g * 8) = pk;
    }
    __syncthreads();

    // ---- GEMM2: h2 = selu(W2 @ h1 + b2), K=64 -> 2 k-slices ----
    short8 h1f[2];
#pragma unroll
    for (int ks = 0; ks < 2; ++ks)
        h1f[ks] = *(const short8*)(bufA + c * 144 + ks * 64 + g * 16);
    f32x4 acc2[4];
#pragma unroll
    for (int mt = 0; mt < 4; ++mt) {
        f32x4 acr = {0.f, 0.f, 0.f, 0.f};
#pragma unroll
        for (int ks = 0; ks < 2; ++ks) {
            const short8 af = Fa[(8 + mt*2 + ks)*64 + lane];
            acr = __builtin_amdgcn_mfma_f32_16x16x32_bf16(af, h1f[ks], acr, 0, 0, 0);
        }
        acc2[mt] = acr;
    }
    __syncthreads();
#pragma unroll
    for (int mt = 0; mt < 4; ++mt) {
        const f32x4 bb = Fb[(4 + mt)*64 + lane];
        unsigned short h4[4];
#pragma unroll
        for (int r = 0; r < 4; ++r) h4[r] = f2bf(selu_f(acc2[mt][r] + bb[r]));
        uint2 pk;
        pk.x = (unsigned)h4[0] | ((unsigned)h4[1] << 16);
        pk.y = (unsigned)h4[2] | ((unsigned)h4[3] << 16);
        *(uint2*)(bufB + c * 144 + mt * 32 + g * 8) = pk;
    }
    __syncthreads();

    // ---- GEMM3: o = W3 @ h2 + b3 (29 rows padded to 32), K=64 -> 2 slices ----
    short8 h2f[2];
#pragma unroll
    for (int ks = 0; ks < 2; ++ks)
        h2f[ks] = *(const short8*)(bufB + c * 144 + ks * 64 + g * 16);
    f32x4 o0 = {0.f,0.f,0.f,0.f}, o1 = {0.f,0.f,0.f,0.f};
#pragma unroll
    for (int ks = 0; ks < 2; ++ks) {
        const short8 af0 = Fa[(16 + ks)*64 + lane];
        o0 = __builtin_amdgcn_mfma_f32_16x16x32_bf16(af0, h2f[ks], o0, 0, 0, 0);
        const short8 af1 = Fa[(18 + ks)*64 + lane];
        o1 = __builtin_amdgcn_mfma_f32_16x16x32_bf16(af1, h2f[ks], o1, 0, 0, 0);
    }
    __syncthreads();   // bufA free again
    {
        const f32x4 bb0 = Fb[8*64 + lane];
        const f32x4 bb1 = Fb[9*64 + lane];
        f32x4 v0, v1;
#pragma unroll
        for (int r = 0; r < 4; ++r) { v0[r] = o0[r] + bb0[r]; v1[r] = o1[r] + bb1[r]; }
        *(f32x4*)(bufA + c * 144 + g * 16)      = v0;
        *(f32x4*)(bufA + c * 144 + 64 + g * 16) = v1;
    }
    __syncthreads();

    // ---- epilogue: quad per point ----
    {
        const int c2 = lane >> 2, part = lane & 3;
        const float* op = (const float*)(bufA + c2 * 144);
        const size_t p = (size_t)tile * 16 + c2;
        if ((int)p < npts) {
            float* dns  = out;
            float* rgbp = out + (size_t)npts;
            float* grdp = out + (size_t)npts * 4;
            float* shp  = out + (size_t)npts * 13;
            if (part == 0) {
                dns[p] = expf(op[0] - 4.f);
                rgbp[p*3+0] = op[1] + 0.5f;
                rgbp[p*3+1] = op[2] + 0.5f;
                rgbp[p*3+2] = op[3] + 0.5f;
            } else {
                const int r = part - 1;
                const float rr = op[1 + r] + 0.5f;
                grdp[p*9 + r*3 + 0] = rr * tanhf(op[4 + r*3 + 0]);
                grdp[p*9 + r*3 + 1] = rr * tanhf(op[4 + r*3 + 1]);
                grdp[p*9 + r*3 + 2] = rr * tanhf(op[4 + r*3 + 2]);
            }
#pragma unroll
            for (int s = 0; s < 4; ++s)
                shp[p*16 + part*4 + s] = op[13 + part*4 + s];
        }
    }
}

extern "C" void kernel_launch(void* const* d_in, const int* in_sizes, int n_in,
                              void* d_out, int out_size, void* d_ws, size_t ws_size,
                              hipStream_t stream) {
    const float* x     = (const float*)d_in[0];
    const float* cr    = (const float*)d_in[1];
    const float* eps   = (const float*)d_in[2];
    const float* table = (const float*)d_in[3];
    const float* W1    = (const float*)d_in[4];
    const float* b1    = (const float*)d_in[5];
    const float* W2    = (const float*)d_in[6];
    const float* b2    = (const float*)d_in[7];
    const float* W3    = (const float*)d_in[8];
    const float* b3    = (const float*)d_in[9];
    float* out = (float*)d_out;

    const int npts   = in_sizes[0] / 3;
    const size_t ntiles = (size_t)(npts + 15) / 16;
    const size_t tblbf_bytes = (size_t)TBL * LVL * 8;     // 5,242,880
    const size_t frag_bytes  = 30720;
    const size_t hswz_bytes  = ntiles * 2048;
    const bool   bfpath = ws_size >= tblbf_bytes + frag_bytes + hswz_bytes;

    char* wsb = (char*)d_ws;
    uint2*          tblbf;
    unsigned short* frag;
    unsigned short* hswz;
    if (bfpath) {
        tblbf = (uint2*)wsb;
        frag  = (unsigned short*)(wsb + tblbf_bytes);
        hswz  = (unsigned short*)(wsb + tblbf_bytes + frag_bytes);
    } else {
        tblbf = (uint2*)table;   // unused in fp32 path
        frag  = (unsigned short*)wsb;
        hswz  = (unsigned short*)(wsb + frag_bytes);
    }

    ResArr res;
    const double bg = exp(log(pow(2.0, 10.0)) / 9.0);
    for (int l = 0; l < LVL; ++l) res.r[l] = (float)floor(16.0 * pow(bg, (double)l));

    if (bfpath)
        hipLaunchKernelGGL(cvt_table, dim3((TBL*LVL + 255)/256), dim3(256), 0, stream,
                           (const float4*)table, tblbf);
    hipLaunchKernelGGL(build_frags, dim3(8), dim3(256), 0, stream,
                       W1, b1, W2, b2, W3, b3, frag);

    const int grid1 = (npts + 31) / 32;
    if (bfpath)
        hipLaunchKernelGGL(ingp_gather<true>, dim3(grid1), dim3(256), 0, stream,
                           x, cr, eps, table, tblbf, hswz, npts, res);
    else
        hipLaunchKernelGGL(ingp_gather<false>, dim3(grid1), dim3(256), 0, stream,
                           x, cr, eps, table, tblbf, hswz, npts, res);

    const int grid2 = (npts + 63) / 64;
    hipLaunchKernelGGL(ingp_mlp, dim3(grid2), dim3(256), 0, stream,
                       hswz, frag, out, npts);
}